// Round 1
// baseline (74.034 us; speedup 1.0000x reference)
//
#include <hip/hip_runtime.h>

#define BATCH 32
#define NROWS 8192
#define IND   128
#define HC    128
#define NEG   0.2f
#define NBLK  32                          // blocks per batch
#define ROWS  64                          // rows per iteration per block
#define ITERS (NROWS / (NBLK * ROWS))     // 4
#define PART_STRIDE 136                   // 4 M + 4 S + 128 P floats

typedef __attribute__((ext_vector_type(8))) short short8;
typedef __attribute__((ext_vector_type(4))) float f32x4;

__device__ __forceinline__ unsigned short f2bf(float f) {
    unsigned u = __float_as_uint(f);
    u += 0x7FFFu + ((u >> 16) & 1u);      // round-to-nearest-even
    return (unsigned short)(u >> 16);
}
__device__ __forceinline__ unsigned pack2(float a, float b) {
    return (unsigned)f2bf(a) | ((unsigned)f2bf(b) << 16);
}

// ---------------- kernel A: x_l for center rows only (B rows) ----------------
__global__ void gat_center(const float* __restrict__ x, const float* __restrict__ Wl,
                           const float* __restrict__ bl, float* __restrict__ xl0)
{
    const int b = blockIdx.x, t = threadIdx.x;   // 128 threads
    __shared__ float xrow[128];
    xrow[t] = x[(size_t)b * NROWS * IND + t];
    __syncthreads();
    float acc = bl[t];
#pragma unroll 16
    for (int k = 0; k < 128; ++k) acc = fmaf(xrow[k], Wl[k * 128 + t], acc);
    xl0[b * 128 + t] = acc;
}

// ---------------- kernel B: x_r GEMM + logits + online-softmax partials ------
__global__ __launch_bounds__(256, 2) void gat_main(
    const float* __restrict__ x, const float* __restrict__ Wr,
    const float* __restrict__ br, const float* __restrict__ att,
    const float* __restrict__ xl0, float* __restrict__ out,
    float* __restrict__ part)
{
    const int tid  = threadIdx.x;
    const int lane = tid & 63;
    const int wv   = tid >> 6;
    const int b    = blockIdx.x >> 5;          // NBLK = 32
    const int blk  = blockIdx.x & (NBLK - 1);

    __shared__ unsigned short WrT[128 * 128];  // 32 KB, W_r^T bf16, swizzled
    __shared__ float ubuf[64 * 132];           // union: bf16 x-tile (16KB) / f32 xr tile (33.8KB)
    __shared__ float w_s[64][4];
    __shared__ float wmax_s[4][4];
    __shared__ float wsum_s[4][4];
    __shared__ float Mrun_s[4], Srun_s[4], scale_s[4];
    __shared__ float Prun_s[128];
    __shared__ float ptmp_s[2][128];
    __shared__ float xl0_s[128], att_s[128], br_s[128];

    unsigned short* Asw = (unsigned short*)ubuf;
    float (*xr_s)[132]  = (float(*)[132])ubuf;

    // stage W_r^T as bf16 with XOR swizzle (k ^= (n&7)<<3) — reads of Wr are coalesced
    for (int i = tid; i < 128 * 128; i += 256) {
        int n = i & 127, k = i >> 7;
        WrT[n * 128 + (k ^ ((n & 7) << 3))] = f2bf(Wr[k * 128 + n]);
    }
    if (tid < 128) {
        xl0_s[tid]  = xl0[b * 128 + tid];
        att_s[tid]  = att[tid];
        br_s[tid]   = br[tid];
        Prun_s[tid] = 0.f;
    }
    if (tid < 4) { Mrun_s[tid] = -INFINITY; Srun_s[tid] = 0.f; }
    __syncthreads();

    const int lr = tid >> 2, lh = tid & 3;     // logits thread mapping: row, head

    for (int it = 0; it < ITERS; ++it) {
        const int n0 = blk * (ITERS * ROWS) + it * ROWS;
        const float* xrow0 = x + ((size_t)b * NROWS + n0) * IND;

        // ---- stage 64x128 f32 x-tile -> bf16 swizzled LDS (coalesced 32B/lane)
#pragma unroll
        for (int ii = 0; ii < 4; ++ii) {
            int ci = tid + ii * 256;           // 1024 chunks of 8 floats
            int r  = ci >> 4;
            int kc = (ci & 15) << 3;
            float4 f0 = *(const float4*)(xrow0 + r * IND + kc);
            float4 f1 = *(const float4*)(xrow0 + r * IND + kc + 4);
            uint4 u;
            u.x = pack2(f0.x, f0.y); u.y = pack2(f0.z, f0.w);
            u.z = pack2(f1.x, f1.y); u.w = pack2(f1.z, f1.w);
            *(uint4*)&Asw[r * 128 + (kc ^ ((r & 7) << 3))] = u;
        }
        __syncthreads();

        // ---- MFMA: each wave computes 16 rows x 128 cols, K=128
        f32x4 acc[8];
#pragma unroll
        for (int i = 0; i < 8; ++i) acc[i] = (f32x4){0.f, 0.f, 0.f, 0.f};
        {
            const int rA   = wv * 16 + (lane & 15);
            const int ksel = lane >> 4;
            short8 afr[4];
#pragma unroll
            for (int ks = 0; ks < 4; ++ks) {
                int k0 = ks * 32 + ksel * 8;
                afr[ks] = *(const short8*)&Asw[rA * 128 + (k0 ^ ((rA & 7) << 3))];
            }
            const int nb = lane & 15;
#pragma unroll
            for (int nt = 0; nt < 8; ++nt) {
                const int n = nt * 16 + nb;
                const unsigned short* bp = &WrT[n * 128];
                const int sw = (n & 7) << 3;
#pragma unroll
                for (int ks = 0; ks < 4; ++ks) {
                    int k0 = ks * 32 + ksel * 8;
                    short8 bfr = *(const short8*)&bp[k0 ^ sw];
                    acc[nt] = __builtin_amdgcn_mfma_f32_16x16x32_bf16(afr[ks], bfr, acc[nt], 0, 0, 0);
                }
            }
        }
        __syncthreads();   // all Asw reads done before union becomes xr_s

        // ---- spill acc -> xr_s (f32) with bias; D layout: row=(lane>>4)*4+reg, col=lane&15
        {
            const int rowb = wv * 16 + (lane >> 4) * 4;
            const int colb = lane & 15;
#pragma unroll
            for (int nt = 0; nt < 8; ++nt) {
                const int col  = nt * 16 + colb;
                const float bias = br_s[col];
#pragma unroll
                for (int rg = 0; rg < 4; ++rg)
                    xr_s[rowb + rg][col] = acc[nt][rg] + bias;
            }
        }
        __syncthreads();

        // ---- coalesced out write (x_r rows; row 0 fixed up by gat_final later)
        {
            float* ob = out + ((size_t)b * NROWS + n0) * HC;
#pragma unroll
            for (int j = 0; j < 8; ++j) {
                int idx = tid + j * 256;
                int row = idx >> 5, c4 = (idx & 31) << 2;
                *(float4*)(ob + row * HC + c4) = *(const float4*)&xr_s[row][c4];
            }
        }

        // ---- logits: thread (lr, lh): sum_c leaky(xl0+xr)*att
        float lg = 0.f;
        {
            const float* xp = &xr_s[lr][lh * 32];
            const float* ap = &att_s[lh * 32];
            const float* qp = &xl0_s[lh * 32];
#pragma unroll
            for (int c4 = 0; c4 < 32; c4 += 4) {
                float4 xv = *(const float4*)(xp + c4);
                float4 av = *(const float4*)(ap + c4);
                float4 qv = *(const float4*)(qp + c4);
                float v0 = qv.x + xv.x; v0 = v0 > 0.f ? v0 : NEG * v0;
                float v1 = qv.y + xv.y; v1 = v1 > 0.f ? v1 : NEG * v1;
                float v2 = qv.z + xv.z; v2 = v2 > 0.f ? v2 : NEG * v2;
                float v3 = qv.w + xv.w; v3 = v3 > 0.f ? v3 : NEG * v3;
                lg = fmaf(v0, av.x, fmaf(v1, av.y, fmaf(v2, av.z, fmaf(v3, av.w, lg))));
            }
        }

        // ---- online softmax update (block-local)
        float mx = lg;
#pragma unroll
        for (int mk = 4; mk < 64; mk <<= 1) mx = fmaxf(mx, __shfl_xor(mx, mk));
        if (lane < 4) wmax_s[wv][lane] = mx;
        __syncthreads();

        const float Mblk = fmaxf(fmaxf(wmax_s[0][lh], wmax_s[1][lh]),
                                 fmaxf(wmax_s[2][lh], wmax_s[3][lh]));
        const float Mold = Mrun_s[lh];
        const float Mnew = fmaxf(Mold, Mblk);
        const float w    = __expf(lg - Mnew);
        w_s[lr][lh] = w;
        float swv = w;
#pragma unroll
        for (int mk = 4; mk < 64; mk <<= 1) swv += __shfl_xor(swv, mk);
        if (lane < 4) wsum_s[wv][lane] = swv;
        __syncthreads();

        if (tid < 4) {                       // tid<4 has lr=0, lh=tid
            const float sc = __expf(Mold - Mnew);
            scale_s[tid] = sc;
            Srun_s[tid]  = Srun_s[tid] * sc +
                (wsum_s[0][tid] + wsum_s[1][tid] + wsum_s[2][tid] + wsum_s[3][tid]);
            Mrun_s[tid]  = Mnew;
        }
        // P partial: thread (half, hc) sums 32 rows of w*xr
        {
            const int hc = tid & 127, half = tid >> 7;
            const int h2 = hc >> 5;
            float accp = 0.f;
#pragma unroll 8
            for (int i2 = 0; i2 < 32; ++i2) {
                int rr = half * 32 + i2;
                accp = fmaf(w_s[rr][h2], xr_s[rr][hc], accp);
            }
            ptmp_s[half][hc] = accp;
        }
        __syncthreads();
        if (tid < 128)
            Prun_s[tid] = Prun_s[tid] * scale_s[tid >> 5] + ptmp_s[0][tid] + ptmp_s[1][tid];
        __syncthreads();
    }

    // ---- write block partials
    float* pb = part + (size_t)(b * NBLK + blk) * PART_STRIDE;
    if (tid < 4)   { pb[tid] = Mrun_s[tid]; pb[4 + tid] = Srun_s[tid]; }
    if (tid < 128) pb[8 + tid] = Prun_s[tid];
}

// ---------------- kernel C: combine partials, write center row ---------------
__global__ void gat_final(const float* __restrict__ part, float* __restrict__ out)
{
    const int b = blockIdx.x, t = threadIdx.x;   // 128 threads: t = h*32+c
    const int h = t >> 5;
    const float* pb = part + (size_t)b * NBLK * PART_STRIDE;
    float Mg = -INFINITY;
    for (int i = 0; i < NBLK; ++i) Mg = fmaxf(Mg, pb[i * PART_STRIDE + h]);
    float Sg = 0.f, Pg = 0.f;
    for (int i = 0; i < NBLK; ++i) {
        const float sc = __expf(pb[i * PART_STRIDE + h] - Mg);
        Sg += pb[i * PART_STRIDE + 4 + h] * sc;
        Pg  = fmaf(pb[i * PART_STRIDE + 8 + t], sc, Pg);
    }
    out[(size_t)b * NROWS * HC + t] = Pg / Sg;
}

extern "C" void kernel_launch(void* const* d_in, const int* in_sizes, int n_in,
                              void* d_out, int out_size, void* d_ws, size_t ws_size,
                              hipStream_t stream)
{
    const float* x   = (const float*)d_in[0];
    const float* Wl  = (const float*)d_in[1];
    const float* bl  = (const float*)d_in[2];
    const float* Wr  = (const float*)d_in[3];
    const float* br  = (const float*)d_in[4];
    const float* att = (const float*)d_in[5];
    float* out = (float*)d_out;

    float* xl0  = (float*)d_ws;                // 32*128 f32
    float* part = xl0 + BATCH * 128;           // 32*32*136 f32

    gat_center<<<BATCH, 128, 0, stream>>>(x, Wl, bl, xl0);
    gat_main<<<BATCH * NBLK, 256, 0, stream>>>(x, Wr, br, att, xl0, out, part);
    gat_final<<<BATCH, 128, 0, stream>>>(part, out);
}